// Round 8
// baseline (796.470 us; speedup 1.0000x reference)
//
#include <hip/hip_runtime.h>

#define NNODES 100000
#define NEDGES 1600000
#define ETOT   1700000   // NEDGES + NNODES self-loops
#define NGRAPH 64
#define NEG    0.2f
#define NB_SCAN 98       // ceil(NNODES / 1024)
#define NPART  8
#define PSZ    ((ETOT + NPART - 1) / NPART)
#define SCAT_BPP 128
#define SCAT_CH  ((ETOT + SCAT_BPP - 1) / SCAT_BPP)

__device__ __forceinline__ float f4get(const float4& v, int j) {
    return j == 0 ? v.x : j == 1 ? v.y : j == 2 ? v.z : v.w;
}

__device__ __forceinline__ unsigned short f2bf(float f) {   // RNE f32->bf16
    unsigned u = __float_as_uint(f);
    u = (u + 0x7fffu + ((u >> 16) & 1u)) >> 16;
    return (unsigned short)u;
}
__device__ __forceinline__ float bf_lo(unsigned u) { return __uint_as_float(u << 16); }
__device__ __forceinline__ float bf_hi(unsigned u) { return __uint_as_float(u & 0xffff0000u); }

// ======================= CSR build =======================
__global__ void k_hist(const int* __restrict__ ei, int* __restrict__ cnt,
                       int* __restrict__ rank) {
    int e = blockIdx.x * 256 + threadIdx.x;
    if (e >= ETOT) return;
    int d = (e < NEDGES) ? ei[NEDGES + e] : e - NEDGES;
    rank[e] = atomicAdd(&cnt[d], 1);
}

__global__ __launch_bounds__(256) void k_scan1(const int* __restrict__ cnt,
                                               int* __restrict__ excl,
                                               int* __restrict__ bsum) {
    __shared__ int tmp[256];
    int t = threadIdx.x;
    int base = blockIdx.x * 1024 + t * 4;
    int v0 = base + 0 < NNODES ? cnt[base + 0] : 0;
    int v1 = base + 1 < NNODES ? cnt[base + 1] : 0;
    int v2 = base + 2 < NNODES ? cnt[base + 2] : 0;
    int v3 = base + 3 < NNODES ? cnt[base + 3] : 0;
    int tot = v0 + v1 + v2 + v3;
    tmp[t] = tot;
    __syncthreads();
    for (int off = 1; off < 256; off <<= 1) {
        int x = (t >= off) ? tmp[t - off] : 0;
        __syncthreads();
        tmp[t] += x;
        __syncthreads();
    }
    int tbase = tmp[t] - tot;
    if (base + 0 < NNODES) excl[base + 0] = tbase;
    if (base + 1 < NNODES) excl[base + 1] = tbase + v0;
    if (base + 2 < NNODES) excl[base + 2] = tbase + v0 + v1;
    if (base + 3 < NNODES) excl[base + 3] = tbase + v0 + v1 + v2;
    if (t == 255) bsum[blockIdx.x] = tmp[255];
}

__global__ void k_scan2(int* __restrict__ bsum) {
    if (threadIdx.x == 0 && blockIdx.x == 0) {
        int acc = 0;
        for (int i = 0; i < NB_SCAN; ++i) { int v = bsum[i]; bsum[i] = acc; acc += v; }
    }
}

__global__ void k_pos(const int* __restrict__ ei, const int* __restrict__ excl,
                      const int* __restrict__ bsum, int* __restrict__ rankpos) {
    int e = blockIdx.x * 256 + threadIdx.x;
    if (e >= ETOT) return;
    int d = (e < NEDGES) ? ei[NEDGES + e] : e - NEDGES;
    rankpos[e] = excl[d] + bsum[d >> 10] + rankpos[e];
}

__global__ __launch_bounds__(256) void k_scatter(const int* __restrict__ ei,
                                                 const int* __restrict__ pos,
                                                 int* __restrict__ csr_src) {
    int p = blockIdx.x & (NPART - 1);
    int chunk = blockIdx.x / NPART;
    int lo = p * PSZ, hi = lo + PSZ;
    int e0 = chunk * SCAT_CH;
    int e1 = e0 + SCAT_CH; if (e1 > ETOT) e1 = ETOT;
    for (int e = e0 + threadIdx.x; e < e1; e += 256) {
        int ps = pos[e];
        if (ps >= lo && ps < hi) {
            int s = (e < NEDGES) ? ei[e] : e - NEDGES;
            csr_src[ps] = s;
        }
    }
}

// ---------------- GEMM1 + fused alphas + bf16 store ----------------
// sW = full W1 (64 KB, coalesced-staged) + sX 32 rows (16 KB) = 80 KB -> 2 blocks/CU
__global__ __launch_bounds__(256) void k_gemm1(const float* __restrict__ x,
                                               const float* __restrict__ W1,
                                               const float* __restrict__ a1s,
                                               const float* __restrict__ a1d,
                                               unsigned short* __restrict__ h1b,
                                               float* __restrict__ as1,
                                               float* __restrict__ ad1) {
    __shared__ float sW[128 * 128];   // 64 KB
    __shared__ float sX[32 * 128];    // 16 KB
    int t = threadIdx.x;
    {
        const float4* W4 = (const float4*)W1;
        float4* sW4 = (float4*)sW;
#pragma unroll
        for (int i = 0; i < 16; ++i) sW4[t + 256 * i] = W4[t + 256 * i];
    }
    int nbase = blockIdx.x * 32;
    int nrows = NNODES - nbase; if (nrows > 32) nrows = 32;
    {
        const float4* X4 = (const float4*)(x + (size_t)nbase * 128);
        float4* sX4 = (float4*)sX;
        for (int i = t; i < nrows * 32; i += 256) sX4[i] = X4[i];
    }
    __syncthreads();

    int colg = t & 31, rowg = t >> 5;
    int c0 = colg * 4;
    float acc[4][4];
#pragma unroll
    for (int i = 0; i < 4; ++i)
        acc[i][0] = acc[i][1] = acc[i][2] = acc[i][3] = 0.f;

    for (int k = 0; k < 128; k += 4) {
        float4 w0 = *(const float4*)&sW[(k + 0) * 128 + c0];
        float4 w1 = *(const float4*)&sW[(k + 1) * 128 + c0];
        float4 w2 = *(const float4*)&sW[(k + 2) * 128 + c0];
        float4 w3 = *(const float4*)&sW[(k + 3) * 128 + c0];
#pragma unroll
        for (int i = 0; i < 4; ++i) {
            float4 xv = *(const float4*)&sX[(rowg + 8 * i) * 128 + k];
            acc[i][0] = fmaf(xv.x, w0.x, acc[i][0]); acc[i][1] = fmaf(xv.x, w0.y, acc[i][1]);
            acc[i][2] = fmaf(xv.x, w0.z, acc[i][2]); acc[i][3] = fmaf(xv.x, w0.w, acc[i][3]);
            acc[i][0] = fmaf(xv.y, w1.x, acc[i][0]); acc[i][1] = fmaf(xv.y, w1.y, acc[i][1]);
            acc[i][2] = fmaf(xv.y, w1.z, acc[i][2]); acc[i][3] = fmaf(xv.y, w1.w, acc[i][3]);
            acc[i][0] = fmaf(xv.z, w2.x, acc[i][0]); acc[i][1] = fmaf(xv.z, w2.y, acc[i][1]);
            acc[i][2] = fmaf(xv.z, w2.z, acc[i][2]); acc[i][3] = fmaf(xv.z, w2.w, acc[i][3]);
            acc[i][0] = fmaf(xv.w, w3.x, acc[i][0]); acc[i][1] = fmaf(xv.w, w3.y, acc[i][1]);
            acc[i][2] = fmaf(xv.w, w3.z, acc[i][2]); acc[i][3] = fmaf(xv.w, w3.w, acc[i][3]);
        }
    }

    int head = colg >> 3;
    float ws0 = a1s[c0], ws1 = a1s[c0 + 1], ws2 = a1s[c0 + 2], ws3 = a1s[c0 + 3];
    float wd0 = a1d[c0], wd1 = a1d[c0 + 1], wd2 = a1d[c0 + 2], wd3 = a1d[c0 + 3];
#pragma unroll
    for (int i = 0; i < 4; ++i) {
        int n = rowg + 8 * i;
        float ps = acc[i][0] * ws0 + acc[i][1] * ws1 + acc[i][2] * ws2 + acc[i][3] * ws3;
        float pd = acc[i][0] * wd0 + acc[i][1] * wd1 + acc[i][2] * wd2 + acc[i][3] * wd3;
        ps += __shfl_xor(ps, 1); ps += __shfl_xor(ps, 2); ps += __shfl_xor(ps, 4);
        pd += __shfl_xor(pd, 1); pd += __shfl_xor(pd, 2); pd += __shfl_xor(pd, 4);
        if (n < nrows) {
            unsigned b0 = f2bf(acc[i][0]), b1 = f2bf(acc[i][1]);
            unsigned b2 = f2bf(acc[i][2]), b3 = f2bf(acc[i][3]);
            uint2 pk; pk.x = b0 | (b1 << 16); pk.y = b2 | (b3 << 16);
            *(uint2*)&h1b[((size_t)(nbase + n)) * 128 + c0] = pk;
            if ((colg & 7) == 0) {
                as1[(size_t)(nbase + n) * 4 + head] = ps;
                ad1[(size_t)(nbase + n) * 4 + head] = pd;
            }
        }
    }
}

// -------- layer-1 aggregation (unchanged) --------
__global__ __launch_bounds__(256) void k_node1(const int* __restrict__ csr_src,
        const int* __restrict__ excl, const int* __restrict__ bsum,
        const int* __restrict__ cnt, const unsigned short* __restrict__ h1b,
        const float4* __restrict__ as1v, const float4* __restrict__ ad1v,
        float* __restrict__ out1) {
    __shared__ float4 exbuf[8][32];
    int t = threadIdx.x;
    int grp = t >> 5, lane = t & 31;
    int node = blockIdx.x * 8 + grp;
    if (node >= NNODES) return;
    int head = lane >> 3;
    int off = excl[node] + bsum[node >> 10];
    int deg = cnt[node];
    float4 adv = ad1v[node];
    float4 dp = make_float4(0.f, 0.f, 0.f, 0.f);
    float4 acc = make_float4(0.f, 0.f, 0.f, 0.f);
    const float* exs = (const float*)&exbuf[grp][0];

    for (int base = 0; base < deg; base += 32) {
        int m = deg - base; if (m > 32) m = 32;
        int sv = 0;
        if (lane < m) {
            sv = csr_src[off + base + lane];
            float4 av = as1v[sv];
            float v; float4 e;
            v = av.x + adv.x; v = v > 0.f ? v : NEG * v; e.x = __expf(v);
            v = av.y + adv.y; v = v > 0.f ? v : NEG * v; e.y = __expf(v);
            v = av.z + adv.z; v = v > 0.f ? v : NEG * v; e.z = __expf(v);
            v = av.w + adv.w; v = v > 0.f ? v : NEG * v; e.w = __expf(v);
            exbuf[grp][lane] = e;
            dp.x += e.x; dp.y += e.y; dp.z += e.z; dp.w += e.w;
        }
        __builtin_amdgcn_wave_barrier();
        for (int i = 0; i < m; ++i) {
            int s = __shfl(sv, i, 32);
            float a = exs[i * 4 + head];
            uint2 hv = *(const uint2*)(h1b + (size_t)s * 128 + lane * 4);
            acc.x = fmaf(bf_lo(hv.x), a, acc.x);
            acc.y = fmaf(bf_hi(hv.x), a, acc.y);
            acc.z = fmaf(bf_lo(hv.y), a, acc.z);
            acc.w = fmaf(bf_hi(hv.y), a, acc.w);
        }
        __builtin_amdgcn_wave_barrier();
    }
#pragma unroll
    for (int msk = 1; msk < 32; msk <<= 1) {
        dp.x += __shfl_xor(dp.x, msk, 32);
        dp.y += __shfl_xor(dp.y, msk, 32);
        dp.z += __shfl_xor(dp.z, msk, 32);
        dp.w += __shfl_xor(dp.w, msk, 32);
    }
    float inv = 1.f / f4get(dp, head);
    float4 o; o.x = acc.x * inv; o.y = acc.y * inv; o.z = acc.z * inv; o.w = acc.w * inv;
    *(float4*)(out1 + (size_t)node * 128 + lane * 4) = o;
}

// ---- GEMM2: round-4 proven inner loop (scalar sW broadcast), 64-row tile ----
// LDS = sW 20 KB + sX 33.8 KB = 53.8 KB -> 2 blocks/CU; VGPR capped by (256,4)
__global__ __launch_bounds__(256, 4) void k_gemm2(const float* __restrict__ in,
                                               const float* __restrict__ W2,
                                               const float* __restrict__ b1,
                                               const float* __restrict__ a2s,
                                               const float* __restrict__ a2d,
                                               unsigned short* __restrict__ h2b,
                                               float* __restrict__ as2,
                                               float* __restrict__ ad2) {
    __shared__ float sW[128 * 40];    // natural layout [k][c], 20 KB
    __shared__ float sX[64 * 132];    // padded rows, 33.8 KB
    int t = threadIdx.x;
    for (int i = t; i < 128 * 40 / 4; i += 256) ((float4*)sW)[i] = ((const float4*)W2)[i];
    int nbase = blockIdx.x * 64;
    int nrows = NNODES - nbase; if (nrows > 64) nrows = 64;
    {
        const float4* X4 = (const float4*)(in + (size_t)nbase * 128);
        for (int i = t; i < nrows * 32; i += 256) {
            int row = i >> 5, c4 = i & 31;
            float4 v = X4[i];
            float4 bb = *(const float4*)&b1[c4 * 4];
            v.x += bb.x; v.y += bb.y; v.z += bb.z; v.w += bb.w;
            v.x = v.x > 0.f ? v.x : __expf(v.x) - 1.f;
            v.y = v.y > 0.f ? v.y : __expf(v.y) - 1.f;
            v.z = v.z > 0.f ? v.z : __expf(v.z) - 1.f;
            v.w = v.w > 0.f ? v.w : __expf(v.w) - 1.f;
            *(float4*)&sX[row * 132 + c4 * 4] = v;
        }
    }
    __syncthreads();

    int colg = t & 7, nodeg = t >> 3;    // 8 col-groups x 32 node-groups
    int c0 = colg * 5;
    int r0 = nodeg, r1 = nodeg + 32;
    float acc[2][5];
#pragma unroll
    for (int i = 0; i < 2; ++i)
#pragma unroll
        for (int c = 0; c < 5; ++c) acc[i][c] = 0.f;

    for (int k = 0; k < 128; k += 4) {
        float4 xv0 = *(const float4*)&sX[r0 * 132 + k];
        float4 xv1 = *(const float4*)&sX[r1 * 132 + k];
#pragma unroll
        for (int j = 0; j < 4; ++j) {
            float w0 = sW[(k + j) * 40 + c0 + 0];
            float w1 = sW[(k + j) * 40 + c0 + 1];
            float w2 = sW[(k + j) * 40 + c0 + 2];
            float w3 = sW[(k + j) * 40 + c0 + 3];
            float w4 = sW[(k + j) * 40 + c0 + 4];
            float xs0 = f4get(xv0, j), xs1 = f4get(xv1, j);
            acc[0][0] = fmaf(xs0, w0, acc[0][0]); acc[1][0] = fmaf(xs1, w0, acc[1][0]);
            acc[0][1] = fmaf(xs0, w1, acc[0][1]); acc[1][1] = fmaf(xs1, w1, acc[1][1]);
            acc[0][2] = fmaf(xs0, w2, acc[0][2]); acc[1][2] = fmaf(xs1, w2, acc[1][2]);
            acc[0][3] = fmaf(xs0, w3, acc[0][3]); acc[1][3] = fmaf(xs1, w3, acc[1][3]);
            acc[0][4] = fmaf(xs0, w4, acc[0][4]); acc[1][4] = fmaf(xs1, w4, acc[1][4]);
        }
    }

    float ws0 = a2s[c0], ws1 = a2s[c0 + 1], ws2 = a2s[c0 + 2], ws3 = a2s[c0 + 3], ws4 = a2s[c0 + 4];
    float wd0 = a2d[c0], wd1 = a2d[c0 + 1], wd2 = a2d[c0 + 2], wd3 = a2d[c0 + 3], wd4 = a2d[c0 + 4];
#pragma unroll
    for (int i = 0; i < 2; ++i) {
        int n = (i == 0) ? r0 : r1;
        float ps = acc[i][0]*ws0 + acc[i][1]*ws1 + acc[i][2]*ws2 + acc[i][3]*ws3 + acc[i][4]*ws4;
        float pd = acc[i][0]*wd0 + acc[i][1]*wd1 + acc[i][2]*wd2 + acc[i][3]*wd3 + acc[i][4]*wd4;
        ps += __shfl_xor(ps, 1); ps += __shfl_xor(ps, 2); ps += __shfl_xor(ps, 4);
        pd += __shfl_xor(pd, 1); pd += __shfl_xor(pd, 2); pd += __shfl_xor(pd, 4);
        if (n < nrows) {
            unsigned short* hp = h2b + (size_t)(nbase + n) * 40 + c0;
#pragma unroll
            for (int c = 0; c < 5; ++c) hp[c] = f2bf(acc[i][c]);
            if (colg == 0) {
                as2[nbase + n] = ps;
                ad2[nbase + n] = pd;
            }
        }
    }
}

// -------- layer-2 aggregation (unchanged) --------
__global__ __launch_bounds__(256) void k_node2(const int* __restrict__ csr_src,
        const int* __restrict__ excl, const int* __restrict__ bsum,
        const int* __restrict__ cnt, const unsigned short* __restrict__ h2b,
        const float* __restrict__ as2, const float* __restrict__ ad2,
        float* __restrict__ out2) {
    int t = threadIdx.x;
    int grp = t >> 4, lane = t & 15;
    int node = blockIdx.x * 16 + grp;
    if (node >= NNODES) return;
    int off = excl[node] + bsum[node >> 10];
    int deg = cnt[node];
    float adv = ad2[node];
    float dp = 0.f;
    float4 acc = make_float4(0.f, 0.f, 0.f, 0.f);

    for (int base = 0; base < deg; base += 16) {
        int m = deg - base; if (m > 16) m = 16;
        int sv = 0; float ex = 0.f;
        if (lane < m) {
            sv = csr_src[off + base + lane];
            float v = as2[sv] + adv;
            v = v > 0.f ? v : NEG * v;
            ex = __expf(v);
            dp += ex;
        }
        for (int i = 0; i < m; ++i) {
            int s = __shfl(sv, i, 16);
            float a = __shfl(ex, i, 16);
            if (lane < 10) {
                uint2 hv = *(const uint2*)(h2b + (size_t)s * 40 + lane * 4);
                acc.x = fmaf(bf_lo(hv.x), a, acc.x);
                acc.y = fmaf(bf_hi(hv.x), a, acc.y);
                acc.z = fmaf(bf_lo(hv.y), a, acc.z);
                acc.w = fmaf(bf_hi(hv.y), a, acc.w);
            }
        }
    }
#pragma unroll
    for (int msk = 1; msk < 16; msk <<= 1) dp += __shfl_xor(dp, msk, 16);
    float inv = 1.f / dp;
    if (lane < 10) {
        float4 o; o.x = acc.x * inv; o.y = acc.y * inv; o.z = acc.z * inv; o.w = acc.w * inv;
        *(float4*)(out2 + (size_t)node * 40 + lane * 4) = o;
    }
}

// -------- global mean pool --------
__global__ __launch_bounds__(256) void k_pool(const float* __restrict__ out2,
        const int* __restrict__ batch, const float* __restrict__ b2,
        float* __restrict__ out) {
    int g = blockIdx.x;
    int lo, hi;
    { int a = 0, b = NNODES; while (a < b) { int m = (a + b) >> 1; if (batch[m] < g) a = m + 1; else b = m; } lo = a; }
    { int a = lo, b = NNODES; while (a < b) { int m = (a + b) >> 1; if (batch[m] < g + 1) a = m + 1; else b = m; } hi = a; }
    int cnt = hi - lo;
    int t = threadIdx.x;
    float sum = 0.f;
    if (t < 240) {
        int c = t % 40, r = t / 40;
        for (int n = lo + r; n < hi; n += 6) sum += out2[(size_t)n * 40 + c];
    }
    __shared__ float red[240];
    if (t < 240) red[t] = sum;
    __syncthreads();
    if (t < 40) {
        float s2 = red[t] + red[t + 40] + red[t + 80] + red[t + 120] + red[t + 160] + red[t + 200];
        out[g * 40 + t] = cnt > 0 ? (s2 / (float)cnt + b2[t]) : 0.f;
    }
}

extern "C" void kernel_launch(void* const* d_in, const int* in_sizes, int n_in,
                              void* d_out, int out_size, void* d_ws, size_t ws_size,
                              hipStream_t stream) {
    const float* x    = (const float*)d_in[0];
    const int*   ei   = (const int*)d_in[1];
    const int*   batch= (const int*)d_in[2];
    const float* W1   = (const float*)d_in[3];
    const float* a1s  = (const float*)d_in[4];
    const float* a1d  = (const float*)d_in[5];
    const float* b1   = (const float*)d_in[6];
    const float* W2   = (const float*)d_in[7];
    const float* a2s  = (const float*)d_in[8];
    const float* a2d  = (const float*)d_in[9];
    const float* b2   = (const float*)d_in[10];
    float* out = (float*)d_out;

    // ---- workspace layout ----
    int* cnt     = (int*)d_ws;                      // N   (memset 0)
    int* excl    = cnt + NNODES;                    // N
    int* boffs   = excl + NNODES;                   // 128
    int* rankpos = boffs + 128;                     // ETOT
    int* csr     = rankpos + ETOT;                  // ETOT
    float* as1   = (float*)(csr + ETOT);            // N*4
    float* ad1   = as1 + (size_t)NNODES * 4;        // N*4
    unsigned short* h1b = (unsigned short*)(ad1 + (size_t)NNODES * 4);  // N*128 bf16
    float* out1  = (float*)(h1b + (size_t)NNODES * 128);                // N*128 f32
    float* as2   = out1 + (size_t)NNODES * 128;     // N
    float* ad2   = as2 + NNODES;                    // N
    unsigned short* h2b = (unsigned short*)(ad2 + NNODES);              // N*40 bf16
    float* out2  = (float*)(h2b + (size_t)NNODES * 40);                 // N*40 f32

    hipMemsetAsync(d_ws, 0, (size_t)NNODES * sizeof(int), stream);

    // CSR build
    k_hist<<<(ETOT + 255) / 256, 256, 0, stream>>>(ei, cnt, rankpos);
    k_scan1<<<NB_SCAN, 256, 0, stream>>>(cnt, excl, boffs);
    k_scan2<<<1, 64, 0, stream>>>(boffs);
    k_pos<<<(ETOT + 255) / 256, 256, 0, stream>>>(ei, excl, boffs, rankpos);
    k_scatter<<<NPART * SCAT_BPP, 256, 0, stream>>>(ei, rankpos, csr);

    // layer 1
    k_gemm1<<<(NNODES + 31) / 32, 256, 0, stream>>>(x, W1, a1s, a1d, h1b, as1, ad1);
    k_node1<<<(NNODES + 7) / 8, 256, 0, stream>>>(csr, excl, boffs, cnt, h1b,
                                                  (const float4*)as1, (const float4*)ad1, out1);

    // layer 2
    k_gemm2<<<(NNODES + 63) / 64, 256, 0, stream>>>(out1, W2, b1, a2s, a2d, h2b, as2, ad2);
    k_node2<<<(NNODES + 15) / 16, 256, 0, stream>>>(csr, excl, boffs, cnt, h2b, as2, ad2, out2);

    // pool
    k_pool<<<NGRAPH, 256, 0, stream>>>(out2, batch, b2, out);
}

// Round 9
// 454.320 us; speedup vs baseline: 1.7531x; 1.7531x over previous
//
#include <hip/hip_runtime.h>

#define NNODES 100000
#define NEDGES 1600000
#define ETOT   1700000   // NEDGES + NNODES self-loops
#define NGRAPH 64
#define NEG    0.2f
#define NB_SCAN 98       // ceil(NNODES / 1024)
#define NPART  8
#define PSZ    ((ETOT + NPART - 1) / NPART)
#define SCAT_BPP 128
#define SCAT_CH  ((ETOT + SCAT_BPP - 1) / SCAT_BPP)

__device__ __forceinline__ float f4get(const float4& v, int j) {
    return j == 0 ? v.x : j == 1 ? v.y : j == 2 ? v.z : v.w;
}

__device__ __forceinline__ unsigned short f2bf(float f) {   // RNE f32->bf16
    unsigned u = __float_as_uint(f);
    u = (u + 0x7fffu + ((u >> 16) & 1u)) >> 16;
    return (unsigned short)u;
}
__device__ __forceinline__ float bf_lo(unsigned u) { return __uint_as_float(u << 16); }
__device__ __forceinline__ float bf_hi(unsigned u) { return __uint_as_float(u & 0xffff0000u); }

// ======================= CSR build =======================
__global__ void k_hist(const int* __restrict__ ei, int* __restrict__ cnt,
                       int* __restrict__ rank) {
    int e = blockIdx.x * 256 + threadIdx.x;
    if (e >= ETOT) return;
    int d = (e < NEDGES) ? ei[NEDGES + e] : e - NEDGES;
    rank[e] = atomicAdd(&cnt[d], 1);
}

__global__ __launch_bounds__(256) void k_scan1(const int* __restrict__ cnt,
                                               int* __restrict__ excl,
                                               int* __restrict__ bsum) {
    __shared__ int tmp[256];
    int t = threadIdx.x;
    int base = blockIdx.x * 1024 + t * 4;
    int v0 = base + 0 < NNODES ? cnt[base + 0] : 0;
    int v1 = base + 1 < NNODES ? cnt[base + 1] : 0;
    int v2 = base + 2 < NNODES ? cnt[base + 2] : 0;
    int v3 = base + 3 < NNODES ? cnt[base + 3] : 0;
    int tot = v0 + v1 + v2 + v3;
    tmp[t] = tot;
    __syncthreads();
    for (int off = 1; off < 256; off <<= 1) {
        int x = (t >= off) ? tmp[t - off] : 0;
        __syncthreads();
        tmp[t] += x;
        __syncthreads();
    }
    int tbase = tmp[t] - tot;
    if (base + 0 < NNODES) excl[base + 0] = tbase;
    if (base + 1 < NNODES) excl[base + 1] = tbase + v0;
    if (base + 2 < NNODES) excl[base + 2] = tbase + v0 + v1;
    if (base + 3 < NNODES) excl[base + 3] = tbase + v0 + v1 + v2;
    if (t == 255) bsum[blockIdx.x] = tmp[255];
}

__global__ void k_scan2(int* __restrict__ bsum) {
    if (threadIdx.x == 0 && blockIdx.x == 0) {
        int acc = 0;
        for (int i = 0; i < NB_SCAN; ++i) { int v = bsum[i]; bsum[i] = acc; acc += v; }
    }
}

__global__ void k_pos(const int* __restrict__ ei, const int* __restrict__ excl,
                      const int* __restrict__ bsum, int* __restrict__ rankpos) {
    int e = blockIdx.x * 256 + threadIdx.x;
    if (e >= ETOT) return;
    int d = (e < NEDGES) ? ei[NEDGES + e] : e - NEDGES;
    rankpos[e] = excl[d] + bsum[d >> 10] + rankpos[e];
}

__global__ __launch_bounds__(256) void k_scatter(const int* __restrict__ ei,
                                                 const int* __restrict__ pos,
                                                 int* __restrict__ csr_src) {
    int p = blockIdx.x & (NPART - 1);
    int chunk = blockIdx.x / NPART;
    int lo = p * PSZ, hi = lo + PSZ;
    int e0 = chunk * SCAT_CH;
    int e1 = e0 + SCAT_CH; if (e1 > ETOT) e1 = ETOT;
    for (int e = e0 + threadIdx.x; e < e1; e += 256) {
        int ps = pos[e];
        if (ps >= lo && ps < hi) {
            int s = (e < NEDGES) ? ei[e] : e - NEDGES;
            csr_src[ps] = s;
        }
    }
}

// ---------------- GEMM1 + fused alphas + bf16 store ----------------
// sW = full W1 (64 KB, coalesced-staged) + sX 32 rows (16 KB) = 80 KB -> 2 blocks/CU
__global__ __launch_bounds__(256) void k_gemm1(const float* __restrict__ x,
                                               const float* __restrict__ W1,
                                               const float* __restrict__ a1s,
                                               const float* __restrict__ a1d,
                                               unsigned short* __restrict__ h1b,
                                               float* __restrict__ as1,
                                               float* __restrict__ ad1) {
    __shared__ float sW[128 * 128];   // 64 KB
    __shared__ float sX[32 * 128];    // 16 KB
    int t = threadIdx.x;
    {
        const float4* W4 = (const float4*)W1;
        float4* sW4 = (float4*)sW;
#pragma unroll
        for (int i = 0; i < 16; ++i) sW4[t + 256 * i] = W4[t + 256 * i];
    }
    int nbase = blockIdx.x * 32;
    int nrows = NNODES - nbase; if (nrows > 32) nrows = 32;
    {
        const float4* X4 = (const float4*)(x + (size_t)nbase * 128);
        float4* sX4 = (float4*)sX;
        for (int i = t; i < nrows * 32; i += 256) sX4[i] = X4[i];
    }
    __syncthreads();

    int colg = t & 31, rowg = t >> 5;
    int c0 = colg * 4;
    float acc[4][4];
#pragma unroll
    for (int i = 0; i < 4; ++i)
        acc[i][0] = acc[i][1] = acc[i][2] = acc[i][3] = 0.f;

    for (int k = 0; k < 128; k += 4) {
        float4 w0 = *(const float4*)&sW[(k + 0) * 128 + c0];
        float4 w1 = *(const float4*)&sW[(k + 1) * 128 + c0];
        float4 w2 = *(const float4*)&sW[(k + 2) * 128 + c0];
        float4 w3 = *(const float4*)&sW[(k + 3) * 128 + c0];
#pragma unroll
        for (int i = 0; i < 4; ++i) {
            float4 xv = *(const float4*)&sX[(rowg + 8 * i) * 128 + k];
            acc[i][0] = fmaf(xv.x, w0.x, acc[i][0]); acc[i][1] = fmaf(xv.x, w0.y, acc[i][1]);
            acc[i][2] = fmaf(xv.x, w0.z, acc[i][2]); acc[i][3] = fmaf(xv.x, w0.w, acc[i][3]);
            acc[i][0] = fmaf(xv.y, w1.x, acc[i][0]); acc[i][1] = fmaf(xv.y, w1.y, acc[i][1]);
            acc[i][2] = fmaf(xv.y, w1.z, acc[i][2]); acc[i][3] = fmaf(xv.y, w1.w, acc[i][3]);
            acc[i][0] = fmaf(xv.z, w2.x, acc[i][0]); acc[i][1] = fmaf(xv.z, w2.y, acc[i][1]);
            acc[i][2] = fmaf(xv.z, w2.z, acc[i][2]); acc[i][3] = fmaf(xv.z, w2.w, acc[i][3]);
            acc[i][0] = fmaf(xv.w, w3.x, acc[i][0]); acc[i][1] = fmaf(xv.w, w3.y, acc[i][1]);
            acc[i][2] = fmaf(xv.w, w3.z, acc[i][2]); acc[i][3] = fmaf(xv.w, w3.w, acc[i][3]);
        }
    }

    int head = colg >> 3;
    float ws0 = a1s[c0], ws1 = a1s[c0 + 1], ws2 = a1s[c0 + 2], ws3 = a1s[c0 + 3];
    float wd0 = a1d[c0], wd1 = a1d[c0 + 1], wd2 = a1d[c0 + 2], wd3 = a1d[c0 + 3];
#pragma unroll
    for (int i = 0; i < 4; ++i) {
        int n = rowg + 8 * i;
        float ps = acc[i][0] * ws0 + acc[i][1] * ws1 + acc[i][2] * ws2 + acc[i][3] * ws3;
        float pd = acc[i][0] * wd0 + acc[i][1] * wd1 + acc[i][2] * wd2 + acc[i][3] * wd3;
        ps += __shfl_xor(ps, 1); ps += __shfl_xor(ps, 2); ps += __shfl_xor(ps, 4);
        pd += __shfl_xor(pd, 1); pd += __shfl_xor(pd, 2); pd += __shfl_xor(pd, 4);
        if (n < nrows) {
            unsigned b0 = f2bf(acc[i][0]), b1 = f2bf(acc[i][1]);
            unsigned b2 = f2bf(acc[i][2]), b3 = f2bf(acc[i][3]);
            uint2 pk; pk.x = b0 | (b1 << 16); pk.y = b2 | (b3 << 16);
            *(uint2*)&h1b[((size_t)(nbase + n)) * 128 + c0] = pk;
            if ((colg & 7) == 0) {
                as1[(size_t)(nbase + n) * 4 + head] = ps;
                ad1[(size_t)(nbase + n) * 4 + head] = pd;
            }
        }
    }
}

// -------- layer-1 aggregation (unchanged) --------
__global__ __launch_bounds__(256) void k_node1(const int* __restrict__ csr_src,
        const int* __restrict__ excl, const int* __restrict__ bsum,
        const int* __restrict__ cnt, const unsigned short* __restrict__ h1b,
        const float4* __restrict__ as1v, const float4* __restrict__ ad1v,
        float* __restrict__ out1) {
    __shared__ float4 exbuf[8][32];
    int t = threadIdx.x;
    int grp = t >> 5, lane = t & 31;
    int node = blockIdx.x * 8 + grp;
    if (node >= NNODES) return;
    int head = lane >> 3;
    int off = excl[node] + bsum[node >> 10];
    int deg = cnt[node];
    float4 adv = ad1v[node];
    float4 dp = make_float4(0.f, 0.f, 0.f, 0.f);
    float4 acc = make_float4(0.f, 0.f, 0.f, 0.f);
    const float* exs = (const float*)&exbuf[grp][0];

    for (int base = 0; base < deg; base += 32) {
        int m = deg - base; if (m > 32) m = 32;
        int sv = 0;
        if (lane < m) {
            sv = csr_src[off + base + lane];
            float4 av = as1v[sv];
            float v; float4 e;
            v = av.x + adv.x; v = v > 0.f ? v : NEG * v; e.x = __expf(v);
            v = av.y + adv.y; v = v > 0.f ? v : NEG * v; e.y = __expf(v);
            v = av.z + adv.z; v = v > 0.f ? v : NEG * v; e.z = __expf(v);
            v = av.w + adv.w; v = v > 0.f ? v : NEG * v; e.w = __expf(v);
            exbuf[grp][lane] = e;
            dp.x += e.x; dp.y += e.y; dp.z += e.z; dp.w += e.w;
        }
        __builtin_amdgcn_wave_barrier();
        for (int i = 0; i < m; ++i) {
            int s = __shfl(sv, i, 32);
            float a = exs[i * 4 + head];
            uint2 hv = *(const uint2*)(h1b + (size_t)s * 128 + lane * 4);
            acc.x = fmaf(bf_lo(hv.x), a, acc.x);
            acc.y = fmaf(bf_hi(hv.x), a, acc.y);
            acc.z = fmaf(bf_lo(hv.y), a, acc.z);
            acc.w = fmaf(bf_hi(hv.y), a, acc.w);
        }
        __builtin_amdgcn_wave_barrier();
    }
#pragma unroll
    for (int msk = 1; msk < 32; msk <<= 1) {
        dp.x += __shfl_xor(dp.x, msk, 32);
        dp.y += __shfl_xor(dp.y, msk, 32);
        dp.z += __shfl_xor(dp.z, msk, 32);
        dp.w += __shfl_xor(dp.w, msk, 32);
    }
    float inv = 1.f / f4get(dp, head);
    float4 o; o.x = acc.x * inv; o.y = acc.y * inv; o.z = acc.z * inv; o.w = acc.w * inv;
    *(float4*)(out1 + (size_t)node * 128 + lane * 4) = o;
}

// ---- GEMM2: restored verbatim round-4 version (proven <=90us) ----
// sW[128][40] natural + sX[128][132] padded = 87.6 KB LDS, 128-row tile
__global__ __launch_bounds__(256) void k_gemm2(const float* __restrict__ in,
                                               const float* __restrict__ W2,
                                               const float* __restrict__ b1,
                                               const float* __restrict__ a2s,
                                               const float* __restrict__ a2d,
                                               unsigned short* __restrict__ h2b,
                                               float* __restrict__ as2,
                                               float* __restrict__ ad2) {
    __shared__ float sW[128 * 40];
    __shared__ float sX[128 * 132];
    int t = threadIdx.x;
    for (int i = t; i < 128 * 40 / 4; i += 256) ((float4*)sW)[i] = ((const float4*)W2)[i];
    int nbase = blockIdx.x * 128;
    int nrows = NNODES - nbase; if (nrows > 128) nrows = 128;
    {
        const float4* X4 = (const float4*)(in + (size_t)nbase * 128);
        for (int i = t; i < nrows * 32; i += 256) {
            int row = i >> 5, c4 = i & 31;
            float4 v = X4[i];
            float4 bb = *(const float4*)&b1[c4 * 4];
            v.x += bb.x; v.y += bb.y; v.z += bb.z; v.w += bb.w;
            v.x = v.x > 0.f ? v.x : __expf(v.x) - 1.f;
            v.y = v.y > 0.f ? v.y : __expf(v.y) - 1.f;
            v.z = v.z > 0.f ? v.z : __expf(v.z) - 1.f;
            v.w = v.w > 0.f ? v.w : __expf(v.w) - 1.f;
            *(float4*)&sX[row * 132 + c4 * 4] = v;
        }
    }
    __syncthreads();

    int colg = t & 7, nodeg = t >> 3;
    int c0 = colg * 5;
    float acc[4][5];
#pragma unroll
    for (int i = 0; i < 4; ++i)
#pragma unroll
        for (int c = 0; c < 5; ++c) acc[i][c] = 0.f;

    for (int k = 0; k < 128; k += 4) {
        float4 xv[4];
#pragma unroll
        for (int i = 0; i < 4; ++i)
            xv[i] = *(const float4*)&sX[(nodeg + 32 * i) * 132 + k];
#pragma unroll
        for (int j = 0; j < 4; ++j) {
            float w0 = sW[(k + j) * 40 + c0 + 0];
            float w1 = sW[(k + j) * 40 + c0 + 1];
            float w2 = sW[(k + j) * 40 + c0 + 2];
            float w3 = sW[(k + j) * 40 + c0 + 3];
            float w4 = sW[(k + j) * 40 + c0 + 4];
#pragma unroll
            for (int i = 0; i < 4; ++i) {
                float xs = f4get(xv[i], j);
                acc[i][0] = fmaf(xs, w0, acc[i][0]);
                acc[i][1] = fmaf(xs, w1, acc[i][1]);
                acc[i][2] = fmaf(xs, w2, acc[i][2]);
                acc[i][3] = fmaf(xs, w3, acc[i][3]);
                acc[i][4] = fmaf(xs, w4, acc[i][4]);
            }
        }
    }

    float ws0 = a2s[c0], ws1 = a2s[c0 + 1], ws2 = a2s[c0 + 2], ws3 = a2s[c0 + 3], ws4 = a2s[c0 + 4];
    float wd0 = a2d[c0], wd1 = a2d[c0 + 1], wd2 = a2d[c0 + 2], wd3 = a2d[c0 + 3], wd4 = a2d[c0 + 4];
#pragma unroll
    for (int i = 0; i < 4; ++i) {
        int n = nodeg + 32 * i;
        float ps = acc[i][0]*ws0 + acc[i][1]*ws1 + acc[i][2]*ws2 + acc[i][3]*ws3 + acc[i][4]*ws4;
        float pd = acc[i][0]*wd0 + acc[i][1]*wd1 + acc[i][2]*wd2 + acc[i][3]*wd3 + acc[i][4]*wd4;
        ps += __shfl_xor(ps, 1); ps += __shfl_xor(ps, 2); ps += __shfl_xor(ps, 4);
        pd += __shfl_xor(pd, 1); pd += __shfl_xor(pd, 2); pd += __shfl_xor(pd, 4);
        if (n < nrows) {
            unsigned short* hp = h2b + (size_t)(nbase + n) * 40 + c0;
#pragma unroll
            for (int c = 0; c < 5; ++c) hp[c] = f2bf(acc[i][c]);
            if (colg == 0) {
                as2[nbase + n] = ps;
                ad2[nbase + n] = pd;
            }
        }
    }
}

// -------- layer-2 aggregation (unchanged) --------
__global__ __launch_bounds__(256) void k_node2(const int* __restrict__ csr_src,
        const int* __restrict__ excl, const int* __restrict__ bsum,
        const int* __restrict__ cnt, const unsigned short* __restrict__ h2b,
        const float* __restrict__ as2, const float* __restrict__ ad2,
        float* __restrict__ out2) {
    int t = threadIdx.x;
    int grp = t >> 4, lane = t & 15;
    int node = blockIdx.x * 16 + grp;
    if (node >= NNODES) return;
    int off = excl[node] + bsum[node >> 10];
    int deg = cnt[node];
    float adv = ad2[node];
    float dp = 0.f;
    float4 acc = make_float4(0.f, 0.f, 0.f, 0.f);

    for (int base = 0; base < deg; base += 16) {
        int m = deg - base; if (m > 16) m = 16;
        int sv = 0; float ex = 0.f;
        if (lane < m) {
            sv = csr_src[off + base + lane];
            float v = as2[sv] + adv;
            v = v > 0.f ? v : NEG * v;
            ex = __expf(v);
            dp += ex;
        }
        for (int i = 0; i < m; ++i) {
            int s = __shfl(sv, i, 16);
            float a = __shfl(ex, i, 16);
            if (lane < 10) {
                uint2 hv = *(const uint2*)(h2b + (size_t)s * 40 + lane * 4);
                acc.x = fmaf(bf_lo(hv.x), a, acc.x);
                acc.y = fmaf(bf_hi(hv.x), a, acc.y);
                acc.z = fmaf(bf_lo(hv.y), a, acc.z);
                acc.w = fmaf(bf_hi(hv.y), a, acc.w);
            }
        }
    }
#pragma unroll
    for (int msk = 1; msk < 16; msk <<= 1) dp += __shfl_xor(dp, msk, 16);
    float inv = 1.f / dp;
    if (lane < 10) {
        float4 o; o.x = acc.x * inv; o.y = acc.y * inv; o.z = acc.z * inv; o.w = acc.w * inv;
        *(float4*)(out2 + (size_t)node * 40 + lane * 4) = o;
    }
}

// -------- global mean pool --------
__global__ __launch_bounds__(256) void k_pool(const float* __restrict__ out2,
        const int* __restrict__ batch, const float* __restrict__ b2,
        float* __restrict__ out) {
    int g = blockIdx.x;
    int lo, hi;
    { int a = 0, b = NNODES; while (a < b) { int m = (a + b) >> 1; if (batch[m] < g) a = m + 1; else b = m; } lo = a; }
    { int a = lo, b = NNODES; while (a < b) { int m = (a + b) >> 1; if (batch[m] < g + 1) a = m + 1; else b = m; } hi = a; }
    int cnt = hi - lo;
    int t = threadIdx.x;
    float sum = 0.f;
    if (t < 240) {
        int c = t % 40, r = t / 40;
        for (int n = lo + r; n < hi; n += 6) sum += out2[(size_t)n * 40 + c];
    }
    __shared__ float red[240];
    if (t < 240) red[t] = sum;
    __syncthreads();
    if (t < 40) {
        float s2 = red[t] + red[t + 40] + red[t + 80] + red[t + 120] + red[t + 160] + red[t + 200];
        out[g * 40 + t] = cnt > 0 ? (s2 / (float)cnt + b2[t]) : 0.f;
    }
}

extern "C" void kernel_launch(void* const* d_in, const int* in_sizes, int n_in,
                              void* d_out, int out_size, void* d_ws, size_t ws_size,
                              hipStream_t stream) {
    const float* x    = (const float*)d_in[0];
    const int*   ei   = (const int*)d_in[1];
    const int*   batch= (const int*)d_in[2];
    const float* W1   = (const float*)d_in[3];
    const float* a1s  = (const float*)d_in[4];
    const float* a1d  = (const float*)d_in[5];
    const float* b1   = (const float*)d_in[6];
    const float* W2   = (const float*)d_in[7];
    const float* a2s  = (const float*)d_in[8];
    const float* a2d  = (const float*)d_in[9];
    const float* b2   = (const float*)d_in[10];
    float* out = (float*)d_out;

    // ---- workspace layout ----
    int* cnt     = (int*)d_ws;                      // N   (memset 0)
    int* excl    = cnt + NNODES;                    // N
    int* boffs   = excl + NNODES;                   // 128
    int* rankpos = boffs + 128;                     // ETOT
    int* csr     = rankpos + ETOT;                  // ETOT
    float* as1   = (float*)(csr + ETOT);            // N*4
    float* ad1   = as1 + (size_t)NNODES * 4;        // N*4
    unsigned short* h1b = (unsigned short*)(ad1 + (size_t)NNODES * 4);  // N*128 bf16
    float* out1  = (float*)(h1b + (size_t)NNODES * 128);                // N*128 f32
    float* as2   = out1 + (size_t)NNODES * 128;     // N
    float* ad2   = as2 + NNODES;                    // N
    unsigned short* h2b = (unsigned short*)(ad2 + NNODES);              // N*40 bf16
    float* out2  = (float*)(h2b + (size_t)NNODES * 40);                 // N*40 f32

    hipMemsetAsync(d_ws, 0, (size_t)NNODES * sizeof(int), stream);

    // CSR build
    k_hist<<<(ETOT + 255) / 256, 256, 0, stream>>>(ei, cnt, rankpos);
    k_scan1<<<NB_SCAN, 256, 0, stream>>>(cnt, excl, boffs);
    k_scan2<<<1, 64, 0, stream>>>(boffs);
    k_pos<<<(ETOT + 255) / 256, 256, 0, stream>>>(ei, excl, boffs, rankpos);
    k_scatter<<<NPART * SCAT_BPP, 256, 0, stream>>>(ei, rankpos, csr);

    // layer 1
    k_gemm1<<<(NNODES + 31) / 32, 256, 0, stream>>>(x, W1, a1s, a1d, h1b, as1, ad1);
    k_node1<<<(NNODES + 7) / 8, 256, 0, stream>>>(csr, excl, boffs, cnt, h1b,
                                                  (const float4*)as1, (const float4*)ad1, out1);

    // layer 2
    k_gemm2<<<(NNODES + 127) / 128, 256, 0, stream>>>(out1, W2, b1, a2s, a2d, h2b, as2, ad2);
    k_node2<<<(NNODES + 15) / 16, 256, 0, stream>>>(csr, excl, boffs, cnt, h2b, as2, ad2, out2);

    // pool
    k_pool<<<NGRAPH, 256, 0, stream>>>(out2, batch, b2, out);
}